// Round 2
// baseline (139.392 us; speedup 1.0000x reference)
//
#include <hip/hip_runtime.h>

// ContrastiveLoss on MI355X (gfx950), B=8192, D=128, labels in [0,2048).
// loss = -(1/cnt) sum_{i: P_i>0} [ S_i/P_i - M - ln Z_i ]
//   Z_i = sum_{j != i} exp(sim_ij - M),  sim = E E^T / T,  M = 1/T (valid shift).
//   S_i = (e_i . g_{lab_i} - e_i . e_i) / T   with class sums g_c (fp32 path).
//   P_i = count[lab_i] - 1.
// Main kernel computes ONLY Z via bf16 MFMA (diag included, corrected in finalize
// using the bf16 self-dot so it matches the MFMA's diagonal term).

#define BATCH 8192
#define DIMK  128
#define INV_T 14.285714285714286f
#define MSUB  14.285714285714286f
#define K1    20.609929155311264f   // INV_T * log2(e)
#define K2    20.609929155311264f   // MSUB  * log2(e)

typedef short bf16x8 __attribute__((ext_vector_type(8)));
typedef float f32x4  __attribute__((ext_vector_type(4)));

__device__ __forceinline__ unsigned short f2bf_rne(float f) {
    unsigned u = __float_as_uint(f);
    u += 0x7FFFu + ((u >> 16) & 1u);
    return (unsigned short)(u >> 16);
}
__device__ __forceinline__ float bf2f(unsigned short b) {
    return __uint_as_float(((unsigned)b) << 16);
}

// Prep: blocks [0,1024) convert fp32->bf16 (4 elems/thread);
//       blocks [1024,1536) compute class sums (1 class per wave, 4/block).
__global__ __launch_bounds__(256) void
prep_kernel(const float* __restrict__ emb, const int* __restrict__ labels,
            ushort* __restrict__ Ebf, float* __restrict__ gsum, int* __restrict__ gcnt) {
    if (blockIdx.x < 1024) {
        int i = blockIdx.x * 256 + threadIdx.x;
        float4 v = ((const float4*)emb)[i];
        ushort4 o;
        o.x = f2bf_rne(v.x); o.y = f2bf_rne(v.y);
        o.z = f2bf_rne(v.z); o.w = f2bf_rne(v.w);
        ((ushort4*)Ebf)[i] = o;
    } else {
        const int lane = threadIdx.x & 63;
        const int wid  = threadIdx.x >> 6;
        const int c    = (blockIdx.x - 1024) * 4 + wid;   // class id, [0,2048)
        float2 acc = {0.f, 0.f};
        int cnt = 0;
        for (int j0 = 0; j0 < BATCH; j0 += 64) {
            int lab = labels[j0 + lane];
            unsigned long long m = __ballot(lab == c);
            cnt += __popcll(m);
            while (m) {
                int j = __ffsll(m) - 1;
                m &= m - 1;
                float2 v = *(const float2*)(emb + (size_t)(j0 + j) * DIMK + lane * 2);
                acc.x += v.x; acc.y += v.y;
            }
        }
        *(float2*)(gsum + (size_t)c * DIMK + lane * 2) = acc;
        if (lane == 0) gcnt[c] = cnt;
    }
}

// Main: Z partials. Grid (32,32), block 256 (4 waves).
// Block = rows [bx*256, +256) x cols [by*256, +256). Wave owns 64 rows (4 m-tiles),
// streams 16 n-tiles of 16 cols. Writes zpart[by*8192 + row] (no atomics).
__global__ __launch_bounds__(256, 4) void
contrastive_main(const ushort* __restrict__ Ebf, float* __restrict__ zpart) {
    const int lane = threadIdx.x & 63;
    const int wid  = threadIdx.x >> 6;
    const int quad = lane >> 4;
    const int l16  = lane & 15;
    const int row_base = blockIdx.x * 256 + wid * 64;
    const int col_base = blockIdx.y * 256;

    bf16x8 afrag[4][4];
#pragma unroll
    for (int mt = 0; mt < 4; ++mt)
#pragma unroll
        for (int kk = 0; kk < 4; ++kk)
            afrag[mt][kk] = *(const bf16x8*)(Ebf + (size_t)(row_base + mt * 16 + l16) * DIMK
                                             + kk * 32 + quad * 8);

    float zacc[16];
#pragma unroll
    for (int s = 0; s < 16; ++s) zacc[s] = 0.f;

    // software-pipelined b-frag loads
    bf16x8 bcur[4], bnext[4];
#pragma unroll
    for (int kk = 0; kk < 4; ++kk)
        bcur[kk] = *(const bf16x8*)(Ebf + (size_t)(col_base + l16) * DIMK + kk * 32 + quad * 8);

    for (int nt = 0; nt < 16; ++nt) {
        const int ncol = col_base + (nt < 15 ? (nt + 1) * 16 : 0) + l16;  // clamp/wrap, harmless
#pragma unroll
        for (int kk = 0; kk < 4; ++kk)
            bnext[kk] = *(const bf16x8*)(Ebf + (size_t)ncol * DIMK + kk * 32 + quad * 8);

#pragma unroll
        for (int mt = 0; mt < 4; ++mt) {
            f32x4 c = {0.f, 0.f, 0.f, 0.f};
#pragma unroll
            for (int kk = 0; kk < 4; ++kk)
                c = __builtin_amdgcn_mfma_f32_16x16x32_bf16(afrag[mt][kk], bcur[kk], c, 0, 0, 0);
#pragma unroll
            for (int r = 0; r < 4; ++r)
                zacc[mt * 4 + r] += __builtin_amdgcn_exp2f(__builtin_fmaf(c[r], K1, -K2));
        }
#pragma unroll
        for (int kk = 0; kk < 4; ++kk) bcur[kk] = bnext[kk];
    }

    // reduce each row-slot across the 16 lanes sharing the row, one store per row
#pragma unroll
    for (int s = 0; s < 16; ++s) {
        float z = zacc[s];
#pragma unroll
        for (int m = 1; m <= 8; m <<= 1) z += __shfl_xor(z, m, 64);
        if (l16 == 0) {
            int row = row_base + (s >> 2) * 16 + quad * 4 + (s & 3);
            zpart[(size_t)blockIdx.y * BATCH + row] = z;
        }
    }
}

// Finalize stage 1: per-row term. Grid 128 blocks x 64 threads (1 wave), 1 row/thread.
__global__ __launch_bounds__(64) void
finalize1(const float* __restrict__ emb, const ushort* __restrict__ Ebf,
          const int* __restrict__ labels, const float* __restrict__ gsum,
          const int* __restrict__ gcnt, const float* __restrict__ zpart,
          float* __restrict__ bpart, int* __restrict__ bcnt) {
    const int r = blockIdx.x * 64 + threadIdx.x;
    const int lab = labels[r];
    const int P = gcnt[lab] - 1;

    float dotg = 0.f, ssd = 0.f, sdbf = 0.f;
    const float4* e4 = (const float4*)(emb + (size_t)r * DIMK);
    const float4* g4 = (const float4*)(gsum + (size_t)lab * DIMK);
    const ushort4* b4 = (const ushort4*)(Ebf + (size_t)r * DIMK);
#pragma unroll 8
    for (int k = 0; k < 32; ++k) {
        float4 ev = e4[k], gv = g4[k];
        dotg += ev.x * gv.x + ev.y * gv.y + ev.z * gv.z + ev.w * gv.w;
        ssd  += ev.x * ev.x + ev.y * ev.y + ev.z * ev.z + ev.w * ev.w;
        ushort4 bv = b4[k];
        float b0 = bf2f(bv.x), b1 = bf2f(bv.y), b2 = bf2f(bv.z), b3 = bf2f(bv.w);
        sdbf += b0 * b0 + b1 * b1 + b2 * b2 + b3 * b3;
    }
    float Z = 0.f;
#pragma unroll 8
    for (int by = 0; by < 32; ++by) Z += zpart[(size_t)by * BATCH + r];
    Z -= __builtin_amdgcn_exp2f(__builtin_fmaf(sdbf, K1, -K2));  // remove diagonal

    const bool has = (P > 0);
    const float S = (dotg - ssd) * INV_T;
    float term = has ? (S / (float)P - MSUB - logf(Z)) : 0.f;
    int c = has ? 1 : 0;
#pragma unroll
    for (int m = 1; m <= 32; m <<= 1) {
        term += __shfl_xor(term, m, 64);
        c    += __shfl_xor(c, m, 64);
    }
    if (threadIdx.x == 0) { bpart[blockIdx.x] = term; bcnt[blockIdx.x] = c; }
}

// Finalize stage 2: reduce 128 block partials -> scalar loss. 1 block x 128 threads.
__global__ __launch_bounds__(128) void
finalize2(const float* __restrict__ bpart, const int* __restrict__ bcnt,
          float* __restrict__ out) {
    __shared__ float sf[2];
    __shared__ int si[2];
    const int t = threadIdx.x;
    float v = bpart[t];
    int c = bcnt[t];
#pragma unroll
    for (int m = 1; m <= 32; m <<= 1) {
        v += __shfl_xor(v, m, 64);
        c += __shfl_xor(c, m, 64);
    }
    if ((t & 63) == 0) { sf[t >> 6] = v; si[t >> 6] = c; }
    __syncthreads();
    if (t == 0) {
        float tot = sf[0] + sf[1];
        int cc = si[0] + si[1];
        out[0] = -tot / (float)(cc > 0 ? cc : 1);
    }
}

extern "C" void kernel_launch(void* const* d_in, const int* in_sizes, int n_in,
                              void* d_out, int out_size, void* d_ws, size_t ws_size,
                              hipStream_t stream) {
    const float* emb  = (const float*)d_in[0];
    const int* labels = (const int*)d_in[1];
    float* out        = (float*)d_out;

    char* ws = (char*)d_ws;
    ushort* Ebf  = (ushort*)ws;                          // 2 MB   (8192*128*2)
    float*  zpart = (float*)(ws + (2u << 20));           // 1 MB   (32*8192*4)
    float*  gsum  = (float*)(ws + (3u << 20));           // 1 MB   (2048*128*4)
    int*    gcnt  = (int*)  (ws + (4u << 20));           // 8 KB
    float*  bpart = (float*)(ws + (4u << 20) + 8192);    // 512 B
    int*    bcnt  = (int*)  (ws + (4u << 20) + 8704);    // 512 B

    prep_kernel<<<1536, 256, 0, stream>>>(emb, labels, Ebf, gsum, gcnt);
    dim3 grid(32, 32);
    contrastive_main<<<grid, 256, 0, stream>>>(Ebf, zpart);
    finalize1<<<128, 64, 0, stream>>>(emb, Ebf, labels, gsum, gcnt, zpart, bpart, bcnt);
    finalize2<<<1, 128, 0, stream>>>(bpart, bcnt, out);
}